// Round 5
// baseline (589.533 us; speedup 1.0000x reference)
//
#include <hip/hip_runtime.h>

#define B_  1024
#define C_  1024
#define HW_ 196
#define A_  8
#define CH_ 256
#define N1_ 2048   // A*CH
#define K2_ 2048   // A*CH

typedef __attribute__((ext_vector_type(8))) short short8;
typedef __attribute__((ext_vector_type(4))) float f32x4;
typedef __attribute__((ext_vector_type(4))) unsigned short us4;

static __device__ __forceinline__ unsigned short f2bf(float x) {
  union { float f; unsigned u; } v; v.f = x;
  unsigned r = (v.u + 0x7FFFu + ((v.u >> 16) & 1u)) >> 16;  // RNE
  return (unsigned short)r;
}

// ---- 1. pool (blocks 0..4095) + both weight transposes (blocks 4096..8191) ----
// pool: forward stream (leaves features TAIL resident in L3 for reverse apply).
__global__ __launch_bounds__(256) void pooltc_k(const float* __restrict__ f,
                                                float* __restrict__ pooled,
                                                unsigned short* __restrict__ pooledb,
                                                const float* __restrict__ fc1_w,
                                                const float* __restrict__ fc2_w,
                                                unsigned short* __restrict__ w1t,
                                                unsigned short* __restrict__ w2t) {
  __shared__ float tile[32][33];
  if (blockIdx.x < 4096) {
    int wid = (blockIdx.x * 256 + threadIdx.x) >> 6;   // 0..16383
    int lane = threadIdx.x & 63;
    int lc = lane < 49 ? lane : 48;                     // clamped: redundant lanes hit same line
    float msk = lane < 49 ? 1.0f : 0.0f;
    unsigned row0 = (unsigned)wid * 64;
    const f32x4* base = (const f32x4*)f;
    for (int it = 0; it < 64; it += 4) {
      unsigned row = row0 + it;
      f32x4 v0 = base[(size_t)(row + 0) * 49 + lc];
      f32x4 v1 = base[(size_t)(row + 1) * 49 + lc];
      f32x4 v2 = base[(size_t)(row + 2) * 49 + lc];
      f32x4 v3 = base[(size_t)(row + 3) * 49 + lc];
      float s0 = (v0.x + v0.y + v0.z + v0.w) * msk;
      float s1 = (v1.x + v1.y + v1.z + v1.w) * msk;
      float s2 = (v2.x + v2.y + v2.z + v2.w) * msk;
      float s3 = (v3.x + v3.y + v3.z + v3.w) * msk;
      #pragma unroll
      for (int off = 32; off > 0; off >>= 1) {
        s0 += __shfl_xor(s0, off, 64);
        s1 += __shfl_xor(s1, off, 64);
        s2 += __shfl_xor(s2, off, 64);
        s3 += __shfl_xor(s3, off, 64);
      }
      if (lane == 0) {
        f32x4 m = {s0, s1, s2, s3};
        m *= (1.0f / 196.0f);
        *(f32x4*)&pooled[row] = m;
        us4 mb = {f2bf(m.x), f2bf(m.y), f2bf(m.z), f2bf(m.w)};
        *(us4*)&pooledb[row] = mb;
      }
    }
  } else {
    int t = blockIdx.x - 4096;
    const float* in; unsigned short* out; int Cc, OS, c0, r0;
    if (t < 2048) {             // fc1_w [A][C][CH] -> w1t [A][CH][C]
      int z = t >> 8, rem = t & 255;
      in  = fc1_w + (size_t)z * (C_ * CH_);
      out = w1t   + (size_t)z * (CH_ * C_);
      Cc = CH_; OS = C_;
      c0 = (rem & 7) * 32;  r0 = (rem >> 3) * 32;
    } else {                    // fc2_w [A][CH][C] -> w2t [C][A*CH]
      t -= 2048;
      int z = t >> 8, rem = t & 255;
      in  = fc2_w + (size_t)z * (CH_ * C_);
      out = w2t   + (size_t)z * CH_;
      Cc = C_; OS = K2_;
      c0 = (rem & 31) * 32; r0 = (rem >> 5) * 32;
    }
    int tx = threadIdx.x & 31, ty = threadIdx.x >> 5;   // 32x8 threads
    #pragma unroll
    for (int i = 0; i < 32; i += 8)
      tile[ty + i][tx] = in[(size_t)(r0 + ty + i) * Cc + c0 + tx];
    __syncthreads();
    #pragma unroll
    for (int i = 0; i < 32; i += 8)
      out[(size_t)(c0 + ty + i) * OS + r0 + tx] = f2bf(tile[tx][ty + i]);
  }
}

// ---------------- 2. softmax gate over experts: one block per b ----------------
__global__ void gate_k(const float* __restrict__ pooled, const float* __restrict__ fc_w,
                       const float* __restrict__ fc_b, float* __restrict__ gate) {
  __shared__ float dots[A_];
  int b = blockIdx.x;
  int wave = threadIdx.x >> 6, lane = threadIdx.x & 63;
  const float* p = pooled + (size_t)b * C_;
  for (int e = wave; e < A_; e += 4) {
    const float* wrow = fc_w + (size_t)e * C_;
    float sum = 0.f;
    for (int c = lane; c < C_; c += 64) sum += p[c] * wrow[c];
    #pragma unroll
    for (int off = 32; off > 0; off >>= 1) sum += __shfl_down(sum, off, 64);
    if (lane == 0) dots[e] = sum + fc_b[e];
  }
  __syncthreads();
  if (threadIdx.x == 0) {
    float mx = dots[0];
    for (int e = 1; e < A_; ++e) mx = fmaxf(mx, dots[e]);
    float ex[A_], se = 0.f;
    for (int e = 0; e < A_; ++e) { ex[e] = __expf(dots[e] - mx); se += ex[e]; }
    float inv = 1.0f / se;
    for (int e = 0; e < A_; ++e) gate[(size_t)b * A_ + e] = ex[e] * inv;
  }
}

// ---------------- 3. GEMM1: gh[b,n] = relu(pooled.fc1_w + b1) * gate ----------------
__global__ __launch_bounds__(256) void gemm1_k(const unsigned short* __restrict__ Ab,
                                               const unsigned short* __restrict__ Bt,
                                               const float* __restrict__ fc1_b,
                                               const float* __restrict__ gate,
                                               unsigned short* __restrict__ gh) {
  int w = threadIdx.x >> 6, lane = threadIdx.x & 63;
  int r = lane & 15, kg = lane >> 4;
  int brow = blockIdx.x * 64 + (w >> 1) * 32;
  int bcol = blockIdx.y * 64 + (w & 1) * 32;
  const short8* Ap0 = (const short8*)(Ab + (size_t)(brow + r) * C_ + kg * 8);
  const short8* Ap1 = (const short8*)(Ab + (size_t)(brow + 16 + r) * C_ + kg * 8);
  const short8* Bp0 = (const short8*)(Bt + (size_t)(bcol + r) * C_ + kg * 8);
  const short8* Bp1 = (const short8*)(Bt + (size_t)(bcol + 16 + r) * C_ + kg * 8);
  f32x4 acc[2][2];
  acc[0][0] = (f32x4){0,0,0,0}; acc[0][1] = acc[0][0];
  acc[1][0] = acc[0][0];        acc[1][1] = acc[0][0];
  #pragma unroll 4
  for (int k = 0; k < C_ / 32; ++k) {
    short8 a0 = Ap0[4 * k], a1 = Ap1[4 * k];
    short8 b0 = Bp0[4 * k], b1 = Bp1[4 * k];
    acc[0][0] = __builtin_amdgcn_mfma_f32_16x16x32_bf16(a0, b0, acc[0][0], 0, 0, 0);
    acc[0][1] = __builtin_amdgcn_mfma_f32_16x16x32_bf16(a0, b1, acc[0][1], 0, 0, 0);
    acc[1][0] = __builtin_amdgcn_mfma_f32_16x16x32_bf16(a1, b0, acc[1][0], 0, 0, 0);
    acc[1][1] = __builtin_amdgcn_mfma_f32_16x16x32_bf16(a1, b1, acc[1][1], 0, 0, 0);
  }
  #pragma unroll
  for (int mi = 0; mi < 2; ++mi)
    #pragma unroll
    for (int ni = 0; ni < 2; ++ni) {
      int col = bcol + ni * 16 + r;
      int aidx = col >> 8;
      float bias = fc1_b[col];
      #pragma unroll
      for (int reg = 0; reg < 4; ++reg) {
        int row = brow + mi * 16 + kg * 4 + reg;
        float val = acc[mi][ni][reg] + bias;
        val = fmaxf(val, 0.f) * gate[row * A_ + aidx];
        gh[(size_t)row * N1_ + col] = f2bf(val);
      }
    }
}

// ---------------- 4. GEMM2: mixed = gh.fc2_w + gate.fc2_b ; s = 1+sigmoid ----------------
__global__ __launch_bounds__(256) void gemm2_k(const unsigned short* __restrict__ Ab,
                                               const unsigned short* __restrict__ Bt,
                                               const float* __restrict__ gate,
                                               const float* __restrict__ fc2_b,
                                               float* __restrict__ s_out) {
  int w = threadIdx.x >> 6, lane = threadIdx.x & 63;
  int r = lane & 15, kg = lane >> 4;
  int brow = blockIdx.x * 64 + (w >> 1) * 32;
  int bcol = blockIdx.y * 64 + (w & 1) * 32;
  const short8* Ap0 = (const short8*)(Ab + (size_t)(brow + r) * K2_ + kg * 8);
  const short8* Ap1 = (const short8*)(Ab + (size_t)(brow + 16 + r) * K2_ + kg * 8);
  const short8* Bp0 = (const short8*)(Bt + (size_t)(bcol + r) * K2_ + kg * 8);
  const short8* Bp1 = (const short8*)(Bt + (size_t)(bcol + 16 + r) * K2_ + kg * 8);
  f32x4 acc[2][2];
  acc[0][0] = (f32x4){0,0,0,0}; acc[0][1] = acc[0][0];
  acc[1][0] = acc[0][0];        acc[1][1] = acc[0][0];
  #pragma unroll 4
  for (int k = 0; k < K2_ / 32; ++k) {
    short8 a0 = Ap0[4 * k], a1 = Ap1[4 * k];
    short8 b0 = Bp0[4 * k], b1 = Bp1[4 * k];
    acc[0][0] = __builtin_amdgcn_mfma_f32_16x16x32_bf16(a0, b0, acc[0][0], 0, 0, 0);
    acc[0][1] = __builtin_amdgcn_mfma_f32_16x16x32_bf16(a0, b1, acc[0][1], 0, 0, 0);
    acc[1][0] = __builtin_amdgcn_mfma_f32_16x16x32_bf16(a1, b0, acc[1][0], 0, 0, 0);
    acc[1][1] = __builtin_amdgcn_mfma_f32_16x16x32_bf16(a1, b1, acc[1][1], 0, 0, 0);
  }
  #pragma unroll
  for (int mi = 0; mi < 2; ++mi)
    #pragma unroll
    for (int ni = 0; ni < 2; ++ni) {
      int col = bcol + ni * 16 + r;
      float b8[A_];
      #pragma unroll
      for (int a = 0; a < A_; ++a) b8[a] = fc2_b[a * C_ + col];
      #pragma unroll
      for (int reg = 0; reg < 4; ++reg) {
        int row = brow + mi * 16 + kg * 4 + reg;
        const float* g = gate + (size_t)row * A_;
        float bias = 0.f;
        #pragma unroll
        for (int a = 0; a < A_; ++a) bias += g[a] * b8[a];
        float mixed = acc[mi][ni][reg] + bias;
        s_out[(size_t)row * C_ + col] = 1.0f + 1.0f / (1.0f + __expf(-mixed));
      }
    }
}

// ---------------- 5. out = features * s[row], TAIL-FIRST (reverse 32MB windows) ----------------
// Plain loads (hit L3-resident features tail left by pool); NT stores (out never re-read,
// don't evict). Within a window the access is forward-coalesced; windows walk high->low.
__global__ __launch_bounds__(256) void apply_k(const f32x4* __restrict__ f,
                                               const float* __restrict__ s,
                                               f32x4* __restrict__ out, unsigned total4) {
  unsigned idx = blockIdx.x * 256 + threadIdx.x;
  unsigned stride = gridDim.x * 256;                 // window size in float4s
  unsigned nwin = (total4 + stride - 1) / stride;
  for (int w = (int)nwin - 1; w >= 0; --w) {
    unsigned i = (unsigned)w * stride + idx;
    if (i < total4) {
      f32x4 v = f[i];
      float m = s[i / 49u];        // 49 float4 per (b,c) row
      v *= m;
      __builtin_nontemporal_store(v, &out[i]);
    }
  }
}

extern "C" void kernel_launch(void* const* d_in, const int* in_sizes, int n_in,
                              void* d_out, int out_size, void* d_ws, size_t ws_size,
                              hipStream_t stream) {
  const float* features = (const float*)d_in[0];
  const float* fc_w  = (const float*)d_in[1];
  const float* fc_b  = (const float*)d_in[2];
  const float* fc1_w = (const float*)d_in[3];
  const float* fc1_b = (const float*)d_in[4];
  const float* fc2_w = (const float*)d_in[5];
  const float* fc2_b = (const float*)d_in[6];
  float* out = (float*)d_out;
  char* ws = (char*)d_ws;

  float*          pooled  = (float*)(ws);                       // 4 MB
  unsigned short* pooledb = (unsigned short*)(ws + 0x400000);   // 2 MB
  float*          gate    = (float*)(ws + 0x600000);            // 32 KB
  unsigned short* gh      = (unsigned short*)(ws + 0x610000);   // 4 MB
  unsigned short* w1t     = (unsigned short*)(ws + 0xA10000);   // 4 MB
  unsigned short* w2t     = (unsigned short*)(ws + 0xE10000);   // 4 MB
  float*          s_buf   = (float*)(ws + 0x1210000);           // 4 MB

  pooltc_k<<<8192, 256, 0, stream>>>(features, pooled, pooledb, fc1_w, fc2_w, w1t, w2t);
  gate_k<<<B_, 256, 0, stream>>>(pooled, fc_w, fc_b, gate);
  gemm1_k<<<dim3(16, 32), 256, 0, stream>>>(pooledb, w1t, fc1_b, gate, gh);
  gemm2_k<<<dim3(16, 16), 256, 0, stream>>>(gh, w2t, gate, fc2_b, s_buf);
  apply_k<<<8192, 256, 0, stream>>>((const f32x4*)features, s_buf, (f32x4*)out,
                                    (unsigned)(out_size / 4));
}

// Round 6
// 554.536 us; speedup vs baseline: 1.0631x; 1.0631x over previous
//
#include <hip/hip_runtime.h>

#define B_  1024
#define C_  1024
#define HW_ 196
#define A_  8
#define CH_ 256
#define N1_ 2048   // A*CH
#define K2_ 2048   // A*CH

typedef __attribute__((ext_vector_type(8))) short short8;
typedef __attribute__((ext_vector_type(4))) float f32x4;

static __device__ __forceinline__ unsigned short f2bf(float x) {
  union { float f; unsigned u; } v; v.f = x;
  unsigned r = (v.u + 0x7FFFu + ((v.u >> 16) & 1u)) >> 16;  // RNE
  return (unsigned short)r;
}

// ---- 1. pool (blocks 0..4095) + both weight transposes (blocks 4096..8191) ----
// pool: ONE ROW PER LANE — zero shuffles, zero masking (49 f32x4 = 784B exactly).
// Loads grouped 4x16B so each cache line is fully consumed back-to-back.
// Result store is a coalesced 64-wide store (no lane-0 serialization).
__global__ __launch_bounds__(256) void pooltc_k(const float* __restrict__ f,
                                                float* __restrict__ pooled,
                                                unsigned short* __restrict__ pooledb,
                                                const float* __restrict__ fc1_w,
                                                const float* __restrict__ fc2_w,
                                                unsigned short* __restrict__ w1t,
                                                unsigned short* __restrict__ w2t) {
  __shared__ float tile[32][33];
  if (blockIdx.x < 4096) {
    unsigned row = blockIdx.x * 256 + threadIdx.x;      // one thread per (b,c) row
    const f32x4* p = (const f32x4*)f + (size_t)row * 49;
    float s = 0.f;
    #pragma unroll 3
    for (int j = 0; j < 12; ++j) {
      f32x4 a = p[4 * j + 0], b = p[4 * j + 1], c = p[4 * j + 2], d = p[4 * j + 3];
      s += (a.x + a.y) + (a.z + a.w);
      s += (b.x + b.y) + (b.z + b.w);
      s += (c.x + c.y) + (c.z + c.w);
      s += (d.x + d.y) + (d.z + d.w);
    }
    f32x4 e = p[48];
    s += (e.x + e.y) + (e.z + e.w);
    float m = s * (1.0f / 196.0f);
    pooled[row] = m;
    pooledb[row] = f2bf(m);
  } else {
    int t = blockIdx.x - 4096;
    const float* in; unsigned short* out; int Cc, OS, c0, r0;
    if (t < 2048) {             // fc1_w [A][C][CH] -> w1t [A][CH][C]
      int z = t >> 8, rem = t & 255;
      in  = fc1_w + (size_t)z * (C_ * CH_);
      out = w1t   + (size_t)z * (CH_ * C_);
      Cc = CH_; OS = C_;
      c0 = (rem & 7) * 32;  r0 = (rem >> 3) * 32;
    } else {                    // fc2_w [A][CH][C] -> w2t [C][A*CH]
      t -= 2048;
      int z = t >> 8, rem = t & 255;
      in  = fc2_w + (size_t)z * (CH_ * C_);
      out = w2t   + (size_t)z * CH_;
      Cc = C_; OS = K2_;
      c0 = (rem & 31) * 32; r0 = (rem >> 5) * 32;
    }
    int tx = threadIdx.x & 31, ty = threadIdx.x >> 5;   // 32x8 threads
    #pragma unroll
    for (int i = 0; i < 32; i += 8)
      tile[ty + i][tx] = in[(size_t)(r0 + ty + i) * Cc + c0 + tx];
    __syncthreads();
    #pragma unroll
    for (int i = 0; i < 32; i += 8)
      out[(size_t)(c0 + ty + i) * OS + r0 + tx] = f2bf(tile[tx][ty + i]);
  }
}

// ---------------- 2. softmax gate over experts: one block per b ----------------
__global__ void gate_k(const float* __restrict__ pooled, const float* __restrict__ fc_w,
                       const float* __restrict__ fc_b, float* __restrict__ gate) {
  __shared__ float dots[A_];
  int b = blockIdx.x;
  int wave = threadIdx.x >> 6, lane = threadIdx.x & 63;
  const float* p = pooled + (size_t)b * C_;
  for (int e = wave; e < A_; e += 4) {
    const float* wrow = fc_w + (size_t)e * C_;
    float sum = 0.f;
    for (int c = lane; c < C_; c += 64) sum += p[c] * wrow[c];
    #pragma unroll
    for (int off = 32; off > 0; off >>= 1) sum += __shfl_down(sum, off, 64);
    if (lane == 0) dots[e] = sum + fc_b[e];
  }
  __syncthreads();
  if (threadIdx.x == 0) {
    float mx = dots[0];
    for (int e = 1; e < A_; ++e) mx = fmaxf(mx, dots[e]);
    float ex[A_], se = 0.f;
    for (int e = 0; e < A_; ++e) { ex[e] = __expf(dots[e] - mx); se += ex[e]; }
    float inv = 1.0f / se;
    for (int e = 0; e < A_; ++e) gate[(size_t)b * A_ + e] = ex[e] * inv;
  }
}

// ---------------- 3. GEMM1: gh[b,n] = relu(pooled.fc1_w + b1) * gate ----------------
__global__ __launch_bounds__(256) void gemm1_k(const unsigned short* __restrict__ Ab,
                                               const unsigned short* __restrict__ Bt,
                                               const float* __restrict__ fc1_b,
                                               const float* __restrict__ gate,
                                               unsigned short* __restrict__ gh) {
  int w = threadIdx.x >> 6, lane = threadIdx.x & 63;
  int r = lane & 15, kg = lane >> 4;
  int brow = blockIdx.x * 64 + (w >> 1) * 32;
  int bcol = blockIdx.y * 64 + (w & 1) * 32;
  const short8* Ap0 = (const short8*)(Ab + (size_t)(brow + r) * C_ + kg * 8);
  const short8* Ap1 = (const short8*)(Ab + (size_t)(brow + 16 + r) * C_ + kg * 8);
  const short8* Bp0 = (const short8*)(Bt + (size_t)(bcol + r) * C_ + kg * 8);
  const short8* Bp1 = (const short8*)(Bt + (size_t)(bcol + 16 + r) * C_ + kg * 8);
  f32x4 acc[2][2];
  acc[0][0] = (f32x4){0,0,0,0}; acc[0][1] = acc[0][0];
  acc[1][0] = acc[0][0];        acc[1][1] = acc[0][0];
  #pragma unroll 4
  for (int k = 0; k < C_ / 32; ++k) {
    short8 a0 = Ap0[4 * k], a1 = Ap1[4 * k];
    short8 b0 = Bp0[4 * k], b1 = Bp1[4 * k];
    acc[0][0] = __builtin_amdgcn_mfma_f32_16x16x32_bf16(a0, b0, acc[0][0], 0, 0, 0);
    acc[0][1] = __builtin_amdgcn_mfma_f32_16x16x32_bf16(a0, b1, acc[0][1], 0, 0, 0);
    acc[1][0] = __builtin_amdgcn_mfma_f32_16x16x32_bf16(a1, b0, acc[1][0], 0, 0, 0);
    acc[1][1] = __builtin_amdgcn_mfma_f32_16x16x32_bf16(a1, b1, acc[1][1], 0, 0, 0);
  }
  #pragma unroll
  for (int mi = 0; mi < 2; ++mi)
    #pragma unroll
    for (int ni = 0; ni < 2; ++ni) {
      int col = bcol + ni * 16 + r;
      int aidx = col >> 8;
      float bias = fc1_b[col];
      #pragma unroll
      for (int reg = 0; reg < 4; ++reg) {
        int row = brow + mi * 16 + kg * 4 + reg;
        float val = acc[mi][ni][reg] + bias;
        val = fmaxf(val, 0.f) * gate[row * A_ + aidx];
        gh[(size_t)row * N1_ + col] = f2bf(val);
      }
    }
}

// ---------------- 4. GEMM2: mixed = gh.fc2_w + gate.fc2_b ; s = 1+sigmoid ----------------
__global__ __launch_bounds__(256) void gemm2_k(const unsigned short* __restrict__ Ab,
                                               const unsigned short* __restrict__ Bt,
                                               const float* __restrict__ gate,
                                               const float* __restrict__ fc2_b,
                                               float* __restrict__ s_out) {
  int w = threadIdx.x >> 6, lane = threadIdx.x & 63;
  int r = lane & 15, kg = lane >> 4;
  int brow = blockIdx.x * 64 + (w >> 1) * 32;
  int bcol = blockIdx.y * 64 + (w & 1) * 32;
  const short8* Ap0 = (const short8*)(Ab + (size_t)(brow + r) * K2_ + kg * 8);
  const short8* Ap1 = (const short8*)(Ab + (size_t)(brow + 16 + r) * K2_ + kg * 8);
  const short8* Bp0 = (const short8*)(Bt + (size_t)(bcol + r) * K2_ + kg * 8);
  const short8* Bp1 = (const short8*)(Bt + (size_t)(bcol + 16 + r) * K2_ + kg * 8);
  f32x4 acc[2][2];
  acc[0][0] = (f32x4){0,0,0,0}; acc[0][1] = acc[0][0];
  acc[1][0] = acc[0][0];        acc[1][1] = acc[0][0];
  #pragma unroll 4
  for (int k = 0; k < K2_ / 32; ++k) {
    short8 a0 = Ap0[4 * k], a1 = Ap1[4 * k];
    short8 b0 = Bp0[4 * k], b1 = Bp1[4 * k];
    acc[0][0] = __builtin_amdgcn_mfma_f32_16x16x32_bf16(a0, b0, acc[0][0], 0, 0, 0);
    acc[0][1] = __builtin_amdgcn_mfma_f32_16x16x32_bf16(a0, b1, acc[0][1], 0, 0, 0);
    acc[1][0] = __builtin_amdgcn_mfma_f32_16x16x32_bf16(a1, b0, acc[1][0], 0, 0, 0);
    acc[1][1] = __builtin_amdgcn_mfma_f32_16x16x32_bf16(a1, b1, acc[1][1], 0, 0, 0);
  }
  #pragma unroll
  for (int mi = 0; mi < 2; ++mi)
    #pragma unroll
    for (int ni = 0; ni < 2; ++ni) {
      int col = bcol + ni * 16 + r;
      float b8[A_];
      #pragma unroll
      for (int a = 0; a < A_; ++a) b8[a] = fc2_b[a * C_ + col];
      #pragma unroll
      for (int reg = 0; reg < 4; ++reg) {
        int row = brow + mi * 16 + kg * 4 + reg;
        const float* g = gate + (size_t)row * A_;
        float bias = 0.f;
        #pragma unroll
        for (int a = 0; a < A_; ++a) bias += g[a] * b8[a];
        float mixed = acc[mi][ni][reg] + bias;
        s_out[(size_t)row * C_ + col] = 1.0f + 1.0f / (1.0f + __expf(-mixed));
      }
    }
}

// ---------------- 5. out = features * s[row] (forward, NT load+store) ----------------
__global__ __launch_bounds__(256) void apply_k(const f32x4* __restrict__ f,
                                               const float* __restrict__ s,
                                               f32x4* __restrict__ out, unsigned total4) {
  unsigned i = blockIdx.x * 256 + threadIdx.x;
  unsigned stride = gridDim.x * 256;
  for (; i < total4; i += stride) {
    f32x4 v = __builtin_nontemporal_load(&f[i]);
    float m = s[i / 49u];          // 49 float4 per (b,c) row
    v *= m;
    __builtin_nontemporal_store(v, &out[i]);
  }
}

extern "C" void kernel_launch(void* const* d_in, const int* in_sizes, int n_in,
                              void* d_out, int out_size, void* d_ws, size_t ws_size,
                              hipStream_t stream) {
  const float* features = (const float*)d_in[0];
  const float* fc_w  = (const float*)d_in[1];
  const float* fc_b  = (const float*)d_in[2];
  const float* fc1_w = (const float*)d_in[3];
  const float* fc1_b = (const float*)d_in[4];
  const float* fc2_w = (const float*)d_in[5];
  const float* fc2_b = (const float*)d_in[6];
  float* out = (float*)d_out;
  char* ws = (char*)d_ws;

  float*          pooled  = (float*)(ws);                       // 4 MB
  unsigned short* pooledb = (unsigned short*)(ws + 0x400000);   // 2 MB
  float*          gate    = (float*)(ws + 0x600000);            // 32 KB
  unsigned short* gh      = (unsigned short*)(ws + 0x610000);   // 4 MB
  unsigned short* w1t     = (unsigned short*)(ws + 0xA10000);   // 4 MB
  unsigned short* w2t     = (unsigned short*)(ws + 0xE10000);   // 4 MB
  float*          s_buf   = (float*)(ws + 0x1210000);           // 4 MB

  pooltc_k<<<8192, 256, 0, stream>>>(features, pooled, pooledb, fc1_w, fc2_w, w1t, w2t);
  gate_k<<<B_, 256, 0, stream>>>(pooled, fc_w, fc_b, gate);
  gemm1_k<<<dim3(16, 32), 256, 0, stream>>>(pooledb, w1t, fc1_b, gate, gh);
  gemm2_k<<<dim3(16, 16), 256, 0, stream>>>(gh, w2t, gate, fc2_b, s_buf);
  apply_k<<<8192, 256, 0, stream>>>((const f32x4*)features, s_buf, (f32x4*)out,
                                    (unsigned)(out_size / 4));
}

// Round 7
// 513.659 us; speedup vs baseline: 1.1477x; 1.0796x over previous
//
#include <hip/hip_runtime.h>

#define B_  1024
#define C_  1024
#define HW_ 196
#define A_  8
#define CH_ 256
#define N1_ 2048   // A*CH
#define K2_ 2048   // A*CH

typedef __attribute__((ext_vector_type(8))) short short8;
typedef __attribute__((ext_vector_type(4))) float f32x4;

// Fragment-tiled layouts: tile (16 rows x 32 k) = 512 bf16, stored as
// [lane=kg*16+r][j=0..7] so one wave short8-load = one full MFMA fragment.
// A-convention: elem (row,k) -> pos ((k>>3)&3)*128 + (row&15)*8 + (k&7)
// B-convention: elem (k,col) -> same with row->col.  Tile index: (t0*KT + kt).
#define KT1 32   // k-tiles in A1/W1 (K=1024)
#define KT2 64   // k-tiles in GH/W2 (K=2048)

static __device__ __forceinline__ unsigned short f2bf(float x) {
  union { float f; unsigned u; } v; v.f = x;
  unsigned r = (v.u + 0x7FFFu + ((v.u >> 16) & 1u)) >> 16;  // RNE
  return (unsigned short)r;
}

// ---- 1. pool (blocks 0..4095) + tiled weight transposes (blocks 4096..8191) ----
__global__ __launch_bounds__(256) void pooltc_k(const float* __restrict__ f,
                                                float* __restrict__ pooled,
                                                const float* __restrict__ fc1_w,
                                                const float* __restrict__ fc2_w,
                                                unsigned short* __restrict__ w1t,
                                                unsigned short* __restrict__ w2t) {
  __shared__ float tile[32][33];
  if (blockIdx.x < 4096) {
    unsigned row = blockIdx.x * 256 + threadIdx.x;      // one thread per (b,c) row
    const f32x4* p = (const f32x4*)f + (size_t)row * 49;
    float s = 0.f;
    #pragma unroll 3
    for (int j = 0; j < 12; ++j) {
      f32x4 a = p[4 * j + 0], b = p[4 * j + 1], c = p[4 * j + 2], d = p[4 * j + 3];
      s += (a.x + a.y) + (a.z + a.w);
      s += (b.x + b.y) + (b.z + b.w);
      s += (c.x + c.y) + (c.z + c.w);
      s += (d.x + d.y) + (d.z + d.w);
    }
    f32x4 e = p[48];
    s += (e.x + e.y) + (e.z + e.w);
    pooled[row] = s * (1.0f / 196.0f);
  } else {
    int t = blockIdx.x - 4096;
    const float* in; unsigned short* outb; int Cc, nt0, kt, KT;
    if (t < 2048) {             // fc1_w [a][k=1024][c=256] -> w1t tiled (n=a*256+c)
      int a = t >> 8, rem = t & 255;
      int c0 = (rem & 7) * 32, k0 = (rem >> 3) * 32;
      in  = fc1_w + (size_t)a * (C_ * CH_) + (size_t)k0 * CH_ + c0;
      Cc = CH_;
      nt0 = a * 16 + (c0 >> 4);  kt = k0 >> 5;  KT = KT1;  outb = w1t;
    } else {                    // fc2_w [a][ch=256][c=1024] -> w2t tiled (k=a*256+ch, n=c)
      t -= 2048;
      int a = t >> 8, rem = t & 255;
      int c0 = (rem & 31) * 32, ch0 = (rem >> 5) * 32;
      in  = fc2_w + (size_t)a * (CH_ * C_) + (size_t)ch0 * C_ + c0;
      Cc = C_;
      nt0 = c0 >> 4;  kt = a * 8 + (ch0 >> 5);  KT = KT2;  outb = w2t;
    }
    int tx = threadIdx.x & 31, ty = threadIdx.x >> 5;   // 32x8 threads, load phase
    #pragma unroll
    for (int i = 0; i < 32; i += 8)
      tile[ty + i][tx] = in[(size_t)(ty + i) * Cc + tx];   // tile[k_local][c_local]
    __syncthreads();
    int tt = threadIdx.x;
    if (tt < 128) {             // 128 threads write 2x 1KB contiguous fragments
      int ct = tt >> 6, kg = (tt >> 4) & 3, r = tt & 15;
      short8 v;
      #pragma unroll
      for (int j = 0; j < 8; ++j)
        v[j] = (short)f2bf(tile[kg * 8 + j][ct * 16 + r]);
      size_t base = ((size_t)(nt0 + ct) * KT + kt) * 512 + (size_t)(kg * 16 + r) * 8;
      *(short8*)(outb + base) = v;
    }
  }
}

// ---- 2. gate (blocks 0..1023) + pooled -> A1 fragment-tiling (blocks 1024..1151) ----
__global__ void gate_k(const float* __restrict__ pooled, const float* __restrict__ fc_w,
                       const float* __restrict__ fc_b, float* __restrict__ gate,
                       unsigned short* __restrict__ a1t) {
  __shared__ float dots[A_];
  if (blockIdx.x < 1024) {
    int b = blockIdx.x;
    int wave = threadIdx.x >> 6, lane = threadIdx.x & 63;
    const float* p = pooled + (size_t)b * C_;
    for (int e = wave; e < A_; e += 4) {
      const float* wrow = fc_w + (size_t)e * C_;
      float sum = 0.f;
      for (int c = lane; c < C_; c += 64) sum += p[c] * wrow[c];
      #pragma unroll
      for (int off = 32; off > 0; off >>= 1) sum += __shfl_down(sum, off, 64);
      if (lane == 0) dots[e] = sum + fc_b[e];
    }
    __syncthreads();
    if (threadIdx.x == 0) {
      float mx = dots[0];
      for (int e = 1; e < A_; ++e) mx = fmaxf(mx, dots[e]);
      float ex[A_], se = 0.f;
      for (int e = 0; e < A_; ++e) { ex[e] = __expf(dots[e] - mx); se += ex[e]; }
      float inv = 1.0f / se;
      for (int e = 0; e < A_; ++e) gate[(size_t)b * A_ + e] = ex[e] * inv;
    }
  } else {
    int h = blockIdx.x - 1024;            // 128 blocks: rt = h>>1, kt half = h&1
    int rt = h >> 1, kt0 = (h & 1) * 16;
    int t = threadIdx.x;
    int e0 = 2 * t;
    int kg = e0 >> 7, r = (e0 >> 3) & 15, j0 = e0 & 7;
    int row = rt * 16 + r;
    for (int kt = kt0; kt < kt0 + 16; ++kt) {
      int col = kt * 32 + kg * 8 + j0;
      float v0 = pooled[(size_t)row * C_ + col];
      float v1 = pooled[(size_t)row * C_ + col + 1];
      size_t base = ((size_t)rt * KT1 + kt) * 512 + e0;
      a1t[base]     = f2bf(v0);
      a1t[base + 1] = f2bf(v1);
    }
  }
}

// ---- 3. GEMM1 (tiled operands): gh = relu(pooled.fc1_w + b1) * gate, tiled out ----
__global__ __launch_bounds__(256) void gemm1_k(const unsigned short* __restrict__ A1,
                                               const unsigned short* __restrict__ W1,
                                               const float* __restrict__ fc1_b,
                                               const float* __restrict__ gate,
                                               unsigned short* __restrict__ gh) {
  int w = threadIdx.x >> 6, lane = threadIdx.x & 63;
  int rt0 = blockIdx.x * 4 + (w >> 1) * 2;       // row-tile (16 rows each)
  int nt0 = blockIdx.y * 4 + (w & 1) * 2;        // col-tile
  const short8* Ap0 = (const short8*)(A1 + (size_t)(rt0    ) * KT1 * 512 + lane * 8);
  const short8* Ap1 = (const short8*)(A1 + (size_t)(rt0 + 1) * KT1 * 512 + lane * 8);
  const short8* Bp0 = (const short8*)(W1 + (size_t)(nt0    ) * KT1 * 512 + lane * 8);
  const short8* Bp1 = (const short8*)(W1 + (size_t)(nt0 + 1) * KT1 * 512 + lane * 8);
  f32x4 acc[2][2];
  acc[0][0] = (f32x4){0,0,0,0}; acc[0][1] = acc[0][0];
  acc[1][0] = acc[0][0];        acc[1][1] = acc[0][0];
  #pragma unroll 4
  for (int kt = 0; kt < KT1; ++kt) {             // tile stride = 512 elems = 64 short8
    short8 a0 = Ap0[64 * kt], a1 = Ap1[64 * kt];
    short8 b0 = Bp0[64 * kt], b1 = Bp1[64 * kt];
    acc[0][0] = __builtin_amdgcn_mfma_f32_16x16x32_bf16(a0, b0, acc[0][0], 0, 0, 0);
    acc[0][1] = __builtin_amdgcn_mfma_f32_16x16x32_bf16(a0, b1, acc[0][1], 0, 0, 0);
    acc[1][0] = __builtin_amdgcn_mfma_f32_16x16x32_bf16(a1, b0, acc[1][0], 0, 0, 0);
    acc[1][1] = __builtin_amdgcn_mfma_f32_16x16x32_bf16(a1, b1, acc[1][1], 0, 0, 0);
  }
  int r = lane & 15, kg = lane >> 4;
  #pragma unroll
  for (int mi = 0; mi < 2; ++mi)
    #pragma unroll
    for (int ni = 0; ni < 2; ++ni) {
      int col = (nt0 + ni) * 16 + r;
      float bias = fc1_b[col];
      int aidx = col >> 8;
      #pragma unroll
      for (int reg = 0; reg < 4; ++reg) {
        int row = (rt0 + mi) * 16 + kg * 4 + reg;
        float val = acc[mi][ni][reg] + bias;
        val = fmaxf(val, 0.f) * gate[row * A_ + aidx];
        // write gh in A-fragment-tiled layout for gemm2
        size_t idx = ((size_t)(row >> 4) * KT2 + (col >> 5)) * 512
                   + (size_t)((col >> 3) & 3) * 128 + (size_t)(row & 15) * 8 + (col & 7);
        gh[idx] = f2bf(val);
      }
    }
}

// ---- 4. GEMM2 (tiled operands): mixed = gh.fc2_w + gate.fc2_b ; s = 1+sigmoid ----
__global__ __launch_bounds__(256) void gemm2_k(const unsigned short* __restrict__ GH,
                                               const unsigned short* __restrict__ W2,
                                               const float* __restrict__ gate,
                                               const float* __restrict__ fc2_b,
                                               float* __restrict__ s_out) {
  int w = threadIdx.x >> 6, lane = threadIdx.x & 63;
  int rt0 = blockIdx.x * 4 + (w >> 1) * 2;
  int nt0 = blockIdx.y * 4 + (w & 1) * 2;
  const short8* Ap0 = (const short8*)(GH + (size_t)(rt0    ) * KT2 * 512 + lane * 8);
  const short8* Ap1 = (const short8*)(GH + (size_t)(rt0 + 1) * KT2 * 512 + lane * 8);
  const short8* Bp0 = (const short8*)(W2 + (size_t)(nt0    ) * KT2 * 512 + lane * 8);
  const short8* Bp1 = (const short8*)(W2 + (size_t)(nt0 + 1) * KT2 * 512 + lane * 8);
  f32x4 acc[2][2];
  acc[0][0] = (f32x4){0,0,0,0}; acc[0][1] = acc[0][0];
  acc[1][0] = acc[0][0];        acc[1][1] = acc[0][0];
  #pragma unroll 4
  for (int kt = 0; kt < KT2; ++kt) {
    short8 a0 = Ap0[64 * kt], a1 = Ap1[64 * kt];
    short8 b0 = Bp0[64 * kt], b1 = Bp1[64 * kt];
    acc[0][0] = __builtin_amdgcn_mfma_f32_16x16x32_bf16(a0, b0, acc[0][0], 0, 0, 0);
    acc[0][1] = __builtin_amdgcn_mfma_f32_16x16x32_bf16(a0, b1, acc[0][1], 0, 0, 0);
    acc[1][0] = __builtin_amdgcn_mfma_f32_16x16x32_bf16(a1, b0, acc[1][0], 0, 0, 0);
    acc[1][1] = __builtin_amdgcn_mfma_f32_16x16x32_bf16(a1, b1, acc[1][1], 0, 0, 0);
  }
  int r = lane & 15, kg = lane >> 4;
  #pragma unroll
  for (int mi = 0; mi < 2; ++mi)
    #pragma unroll
    for (int ni = 0; ni < 2; ++ni) {
      int col = (nt0 + ni) * 16 + r;
      float b8[A_];
      #pragma unroll
      for (int a = 0; a < A_; ++a) b8[a] = fc2_b[a * C_ + col];
      #pragma unroll
      for (int reg = 0; reg < 4; ++reg) {
        int row = (rt0 + mi) * 16 + kg * 4 + reg;
        const float* g = gate + (size_t)row * A_;
        float bias = 0.f;
        #pragma unroll
        for (int a = 0; a < A_; ++a) bias += g[a] * b8[a];
        float mixed = acc[mi][ni][reg] + bias;
        s_out[(size_t)row * C_ + col] = 1.0f + 1.0f / (1.0f + __expf(-mixed));
      }
    }
}

// ---------------- 5. out = features * s[row] (forward, NT load+store) ----------------
__global__ __launch_bounds__(256) void apply_k(const f32x4* __restrict__ f,
                                               const float* __restrict__ s,
                                               f32x4* __restrict__ out, unsigned total4) {
  unsigned i = blockIdx.x * 256 + threadIdx.x;
  unsigned stride = gridDim.x * 256;
  for (; i < total4; i += stride) {
    f32x4 v = __builtin_nontemporal_load(&f[i]);
    float m = s[i / 49u];          // 49 float4 per (b,c) row
    v *= m;
    __builtin_nontemporal_store(v, &out[i]);
  }
}

extern "C" void kernel_launch(void* const* d_in, const int* in_sizes, int n_in,
                              void* d_out, int out_size, void* d_ws, size_t ws_size,
                              hipStream_t stream) {
  const float* features = (const float*)d_in[0];
  const float* fc_w  = (const float*)d_in[1];
  const float* fc_b  = (const float*)d_in[2];
  const float* fc1_w = (const float*)d_in[3];
  const float* fc1_b = (const float*)d_in[4];
  const float* fc2_w = (const float*)d_in[5];
  const float* fc2_b = (const float*)d_in[6];
  float* out = (float*)d_out;
  char* ws = (char*)d_ws;

  float*          pooled = (float*)(ws);                       // 4 MB
  unsigned short* a1t    = (unsigned short*)(ws + 0x400000);   // 2 MB (A1 tiled)
  float*          gate   = (float*)(ws + 0x600000);            // 32 KB
  unsigned short* gh     = (unsigned short*)(ws + 0x610000);   // 4 MB (tiled)
  unsigned short* w1t    = (unsigned short*)(ws + 0xA10000);   // 4 MB (tiled)
  unsigned short* w2t    = (unsigned short*)(ws + 0xE10000);   // 4 MB (tiled)
  float*          s_buf  = (float*)(ws + 0x1210000);           // 4 MB

  pooltc_k<<<8192, 256, 0, stream>>>(features, pooled, fc1_w, fc2_w, w1t, w2t);
  gate_k<<<1152, 256, 0, stream>>>(pooled, fc_w, fc_b, gate, a1t);
  gemm1_k<<<dim3(16, 32), 256, 0, stream>>>(a1t, w1t, fc1_b, gate, gh);
  gemm2_k<<<dim3(16, 16), 256, 0, stream>>>(gh, w2t, gate, fc2_b, s_buf);
  apply_k<<<8192, 256, 0, stream>>>((const f32x4*)features, s_buf, (f32x4*)out,
                                    (unsigned)(out_size / 4));
}